// Round 5
// baseline (604.954 us; speedup 1.0000x reference)
//
#include <hip/hip_runtime.h>
#include <hip/hip_bf16.h>

using bf16 = __bf16;
typedef __bf16 bf16x8 __attribute__((ext_vector_type(8)));
typedef __bf16 bf16x4 __attribute__((ext_vector_type(4)));
typedef float  f32x4  __attribute__((ext_vector_type(4)));

#define MFMA16(a, b, c) __builtin_amdgcn_mfma_f32_16x16x32_bf16((a), (b), (c), 0, 0, 0)

// packed weight layout (bf16 element offsets in d_ws); fragment order:
// element j of lane L -> W[kt*32 + (L>>4)*8 + j][nt*16 + (L&15)], zero-padded.
constexpr int P0  = 0;
constexpr int P1  = 16384;
constexpr int P2  = 81920;
constexpr int P3  = 147456;
constexpr int P4  = 212992;
constexpr int P5  = 278528;
constexpr int P6  = 360448;
constexpr int P7  = 425984;
constexpr int PD  = 491520;
constexpr int PC0 = 495616;
constexpr int PC1 = 532480;

constexpr int NPTS = 4096 * 128;
constexpr int MT = 64;         // points per block; H=40960 B -> 4 blocks/CU (full LDS)
constexpr int PTILES = MT / 16;
constexpr int NCHUNK = 40;     // 40 chunks of 8 cols
constexpr int CH = MT * 8;     // 512 bf16 elements per chunk block (1024 B)

// H layout TRANSPOSED: element (point p, col c) at (c>>3)*CH + p*8 + (c&7).
// All LDS addresses are base + compile-time immediate; reads bank-balanced.
// Keep CG=8/NPG=1 (weights once per point-tile) -- R4 showed weight re-reads
// cost more than af re-reads; this round buys latency hiding (8 waves/SIMD,
// 4 independent blocks/CU) instead of trading traffic.

// ------------------------------- pack kernel -------------------------------
struct PackArgs {
    const float* src[11];
    int K[11], N[11], Ntiles[11], tasks[11], dstoff[11];
};

__global__ void nerf_pack(PackArgs pa, bf16* __restrict__ dst) {
    int idx = blockIdx.x * 256 + threadIdx.x;
    for (int l = 0; l < 11; ++l) {
        if (idx < pa.tasks[l]) {
            const int lane = idx & 63;
            const int blk  = idx >> 6;
            const int nt   = blk % pa.Ntiles[l];
            const int kt   = blk / pa.Ntiles[l];
            const int kb   = kt * 32 + (lane >> 4) * 8;
            const int n    = nt * 16 + (lane & 15);
            const float* s = pa.src[l];
            const int K = pa.K[l], N = pa.N[l];
            bf16x8 v;
#pragma unroll
            for (int j = 0; j < 8; ++j) {
                int k = kb + j;
                v[j] = (bf16)((k < K && n < N) ? s[(size_t)k * N + n] : 0.f);
            }
            *(bf16x8*)(dst + pa.dstoff[l] + (size_t)idx * 8) = v;
            return;
        }
        idx -= pa.tasks[l];
    }
}

// ------------------------------- layer -------------------------------------
// Block = 512 threads = 8 waves, M=64 points. In-place C = act(H @ Wp + b).
// Operands swapped: D[m=chan][n=point].
// N=256: CG=8, NT_W=2, NPG=1, PT_W=4 -> each weight fragment loaded once/block.
// COFF = source column offset (compile-time, folds into read base).
template <int KP, int N, bool RELU, int MODE, bool HAZARD, int COFF>
__device__ __forceinline__ void layer(bf16* H,
                                      const bf16* __restrict__ wp,
                                      const float* __restrict__ bias,
                                      float* __restrict__ gout, int m0) {
    constexpr int NW     = 8;
    constexpr int NTILES = N / 16;
    constexpr int NT_W   = (NTILES >= 8) ? 2 : 1;
    constexpr int CG     = NTILES / NT_W;            // chan wave-groups: 16->8, 8->4, 1->1
    static_assert(CG <= NW && NW % CG == 0, "wave split");
    constexpr int NPG0   = NW / CG;                  // point wave-groups (raw)
    constexpr int NPG    = (NPG0 > PTILES) ? PTILES : NPG0;
    constexpr int PT_W   = PTILES / NPG;             // point tiles per wave
    static_assert(NPG == NPG0 || (MODE != 0 && !HAZARD),
                  "idle waves only allowed in barrier-free modes");
    constexpr int KT = KP / 32;
    constexpr int C0 = COFF >> 3;                    // starting chunk

    const int tid  = threadIdx.x;
    const int lane = tid & 63;
    const int w    = tid >> 6;

    if constexpr (NPG != NPG0) {
        if (w / CG >= NPG) return;   // idle wave (no barriers in this mode)
    }

    const int l15  = lane & 15;
    const int quad = lane >> 4;
    const int nt0  = (w % CG) * NT_W;
    const int pt0  = (w / CG) * PT_W;

    // af read base: chunk (C0 + kt*4 + quad), point (pt0+pt)*16 + l15.
    const bf16* ar = H + (C0 + quad) * CH + (pt0 * 16 + l15) * 8;

    f32x4 acc[PT_W][NT_W];
    if constexpr (MODE == 0) {
#pragma unroll
        for (int nt = 0; nt < NT_W; ++nt) {
            f32x4 b4 = *(const f32x4*)(bias + (nt0 + nt) * 16 + quad * 4);
#pragma unroll
            for (int pt = 0; pt < PT_W; ++pt) acc[pt][nt] = b4;
        }
    } else if constexpr (MODE == 1) {
        const float bv = bias[0];
        f32x4 t = {bv, bv, bv, bv};
#pragma unroll
        for (int pt = 0; pt < PT_W; ++pt) acc[pt][0] = t;
    } else {
        f32x4 t = {bias[0], bias[1], bias[2], 0.f};
#pragma unroll
        for (int pt = 0; pt < PT_W; ++pt) acc[pt][0] = t;
    }

#pragma unroll 2
    for (int kt = 0; kt < KT; ++kt) {
        bf16x8 wf[NT_W];
#pragma unroll
        for (int nt = 0; nt < NT_W; ++nt)
            wf[nt] = *(const bf16x8*)(wp + ((size_t)(kt * NTILES + nt0 + nt) * 64 + lane) * 8);
#pragma unroll
        for (int pt = 0; pt < PT_W; ++pt) {
            bf16x8 af = *(const bf16x8*)(ar + kt * (4 * CH) + pt * 128);
#pragma unroll
            for (int nt = 0; nt < NT_W; ++nt)
                acc[pt][nt] = MFMA16(wf[nt], af, acc[pt][nt]);
        }
    }
    if (HAZARD) __syncthreads();   // all in-place reads done before writes

    if constexpr (MODE == 0) {
        // write: col c = (nt0+nt)*16 + quad*4 + r, point = (pt0+pt)*16 + l15
        // chunk = (nt0+nt)*2 + (quad>>1), in-chunk col = (quad&1)*4 + r
        bf16* wr = H + (nt0 * 2 + (quad >> 1)) * CH + (pt0 * 16 + l15) * 8 + (quad & 1) * 4;
#pragma unroll
        for (int pt = 0; pt < PT_W; ++pt) {
#pragma unroll
            for (int nt = 0; nt < NT_W; ++nt) {
                f32x4 a = acc[pt][nt];
                bf16x4 o;
#pragma unroll
                for (int r = 0; r < 4; ++r) {
                    float v = a[r];
                    if (RELU) v = v > 0.f ? v : 0.f;
                    o[r] = (bf16)v;
                }
                *(bf16x4*)(wr + nt * (2 * CH) + pt * 128) = o;
            }
        }
        __syncthreads();           // writes visible before next layer reads
    } else if constexpr (MODE == 1) {
        if (quad == 0) {
#pragma unroll
            for (int pt = 0; pt < PT_W; ++pt)
                gout[m0 + (pt0 + pt) * 16 + l15] = acc[pt][0][0];
        }
    } else {
        if (quad == 0) {
#pragma unroll
            for (int pt = 0; pt < PT_W; ++pt) {
                const size_t p3 = (size_t)(m0 + (pt0 + pt) * 16 + l15) * 3;
                gout[p3 + 0] = acc[pt][0][0];
                gout[p3 + 1] = acc[pt][0][1];
                gout[p3 + 2] = acc[pt][0][2];
            }
        }
    }
}

// ------------------------------- main kernel -------------------------------
__global__ __launch_bounds__(512, 8)
void nerf_main(const float* __restrict__ pos, const float* __restrict__ dir,
               const float* __restrict__ b0, const float* __restrict__ b1,
               const float* __restrict__ b2, const float* __restrict__ b3,
               const float* __restrict__ b4, const float* __restrict__ b5,
               const float* __restrict__ b6, const float* __restrict__ b7,
               const float* __restrict__ bd, const float* __restrict__ bc0,
               const float* __restrict__ bc1,
               const bf16* __restrict__ wpk, float* __restrict__ out) {
    __shared__ __align__(16) bf16 H[NCHUNK * CH];   // 40960 B -> 4 blocks/CU

    const int m0 = blockIdx.x * MT;
    const int tid = threadIdx.x;

    // positional encoding -> cols 256..315; 316..319 zeroed (K-pad).
    // 8 threads/row; each writes 1 contiguous 16B chunk (8 cols).
    {
        const int row = tid >> 3;          // 0..63
        const int sub = tid & 7;
        const size_t pb = (size_t)(m0 + row) * 3;
        float xs[3] = { pos[pb], pos[pb + 1], pos[pb + 2] };
        bf16x8 v;
#pragma unroll
        for (int j = 0; j < 8; ++j) {
            const int col = sub * 8 + j;   // 0..63
            float t = 0.f;
            if (col < 60) {
                const int c = col / 20, rem = col % 20, s = rem / 10, i = rem % 10;
                const float arg = xs[c] * (float)(1 << i);
                t = s ? __cosf(arg) : __sinf(arg);
            }
            v[j] = (bf16)t;
        }
        *(bf16x8*)(H + (32 + sub) * CH + row * 8) = v;
    }
    __syncthreads();

    // trunk, in-place; embed_pos lives in cols 256..315 until L5 consumes it
    layer<64,  256, true, 0, false, 256>(H, wpk + P0, b0, nullptr, m0);
    layer<256, 256, true, 0, true,  0  >(H, wpk + P1, b1, nullptr, m0);
    layer<256, 256, true, 0, true,  0  >(H, wpk + P2, b2, nullptr, m0);
    layer<256, 256, true, 0, true,  0  >(H, wpk + P3, b3, nullptr, m0);
    layer<256, 256, true, 0, true,  0  >(H, wpk + P4, b4, nullptr, m0);
    layer<320, 256, true, 0, true,  0  >(H, wpk + P5, b5, nullptr, m0);  // skip concat
    layer<256, 256, true, 0, true,  0  >(H, wpk + P6, b6, nullptr, m0);
    layer<256, 256, true, 0, true,  0  >(H, wpk + P7, b7, nullptr, m0);  // h8 -> cols 0..255

    // density head: reads chunks 0..31, writes global only (waves 4..7 idle)
    layer<256, 16, false, 1, false, 0>(H, wpk + PD, bd, out, m0);

    // dir encoding -> cols 256..279; 280..287 zeroed (c0 K-pad); chunks 32..35
    // disjoint from density's reads -> no barrier before.
    {
        const int row = tid >> 3;
        const int sub = tid & 7;
        if (sub < 4) {
            const size_t db = (size_t)(m0 + row) * 3;
            float ds[3] = { dir[db], dir[db + 1], dir[db + 2] };
            bf16x8 v;
#pragma unroll
            for (int j = 0; j < 8; ++j) {
                const int col = sub * 8 + j;   // 0..31
                float t = 0.f;
                if (col < 24) {
                    const int c = col / 8, rem = col % 8, s = rem / 4, i = rem % 4;
                    const float arg = ds[c] * (float)(1 << i);
                    t = s ? __cosf(arg) : __sinf(arg);
                }
                v[j] = (bf16)t;
            }
            *(bf16x8*)(H + (32 + sub) * CH + row * 8) = v;
        }
    }
    __syncthreads();

    // color head
    layer<288, 128, true, 0, true,  0>(H, wpk + PC0, bc0, nullptr, m0); // c0 -> cols 0..127
    layer<128, 16, false, 2, false, 0>(H, wpk + PC1, bc1, out + NPTS, m0);
}

// Loud sentinel if harness I/O layout differs from expectation.
__global__ void nerf_sentinel(float* __restrict__ out, float val) {
    if (threadIdx.x == 0 && blockIdx.x == 0) out[0] = val;
}

// ------------------------------- launcher ----------------------------------
extern "C" void kernel_launch(void* const* d_in, const int* in_sizes, int n_in,
                              void* d_out, int out_size, void* d_ws, size_t ws_size,
                              hipStream_t stream) {
    static const int exp2[24] = {
        1572864, 1572864,
        15360, 256, 65536, 256, 65536, 256, 65536, 256,
        65536, 256, 80896, 256, 65536, 256, 65536, 256,
        256, 1, 35840, 128, 384, 3
    };
    int bad = -1;
    if (n_in != 24) bad = 99;
    else {
        for (int i = 0; i < 24; ++i)
            if (in_sizes[i] != exp2[i]) { bad = i; break; }
    }
    if (bad < 0 && out_size != NPTS * 4) bad = 97;
    if (bad >= 0) {
        nerf_sentinel<<<1, 64, 0, stream>>>((float*)d_out, 20000.f + 100.f * bad);
        return;
    }

    static const int wi[11] = {2, 4, 6, 8, 10, 12, 14, 16, 18, 20, 22};
    static const int Ks[11] = {60, 256, 256, 256, 256, 316, 256, 256, 256, 280, 128};
    static const int Ns[11] = {256, 256, 256, 256, 256, 256, 256, 256, 1, 128, 3};
    static const int Kp[11] = {64, 256, 256, 256, 256, 320, 256, 256, 256, 288, 128};
    static const int Np[11] = {256, 256, 256, 256, 256, 256, 256, 256, 16, 128, 16};

    PackArgs pa;
    int off = 0, total_tasks = 0;
    for (int l = 0; l < 11; ++l) {
        pa.src[l]    = (const float*)d_in[wi[l]];
        pa.K[l]      = Ks[l];
        pa.N[l]      = Ns[l];
        pa.Ntiles[l] = Np[l] / 16;
        pa.tasks[l]  = (Kp[l] / 32) * (Np[l] / 16) * 64;
        pa.dstoff[l] = off;
        off += pa.tasks[l] * 8;
        total_tasks += pa.tasks[l];
    }
    bf16* wpk = (bf16*)d_ws;

    nerf_pack<<<(total_tasks + 255) / 256, 256, 0, stream>>>(pa, wpk);

    nerf_main<<<NPTS / MT, 512, 0, stream>>>(
        (const float*)d_in[0], (const float*)d_in[1],
        (const float*)d_in[3], (const float*)d_in[5], (const float*)d_in[7],
        (const float*)d_in[9], (const float*)d_in[11], (const float*)d_in[13],
        (const float*)d_in[15], (const float*)d_in[17], (const float*)d_in[19],
        (const float*)d_in[21], (const float*)d_in[23],
        wpk, (float*)d_out);
}

// Round 6
// 533.113 us; speedup vs baseline: 1.1348x; 1.1348x over previous
//
#include <hip/hip_runtime.h>
#include <hip/hip_bf16.h>

using bf16 = __bf16;
typedef __bf16 bf16x8 __attribute__((ext_vector_type(8)));
typedef __bf16 bf16x4 __attribute__((ext_vector_type(4)));
typedef float  f32x4  __attribute__((ext_vector_type(4)));

#define MFMA16(a, b, c) __builtin_amdgcn_mfma_f32_16x16x32_bf16((a), (b), (c), 0, 0, 0)

// packed weight layout (bf16 element offsets in d_ws); fragment order:
// element j of lane L -> W[kt*32 + (L>>4)*8 + j][nt*16 + (L&15)], zero-padded.
constexpr int P0  = 0;
constexpr int P1  = 16384;
constexpr int P2  = 81920;
constexpr int P3  = 147456;
constexpr int P4  = 212992;
constexpr int P5  = 278528;
constexpr int P6  = 360448;
constexpr int P7  = 425984;
constexpr int PD  = 491520;
constexpr int PC0 = 495616;
constexpr int PC1 = 532480;

constexpr int NPTS = 4096 * 128;
constexpr int MT = 128;        // points per block
constexpr int PTILES = MT / 16;
constexpr int NCHUNK = 40;     // 40 chunks of 8 cols
constexpr int CH = MT * 8;     // 1024 bf16 elements per chunk block (2048 B)

// H layout TRANSPOSED: element (point p, col c) at (c>>3)*CH + p*8 + (c&7).
// All LDS addresses are base + compile-time immediate; reads bank-balanced.
//
// NW=4 FAT WAVES: af_mult x wf_mult = tiles/tiles_per_wave = NW. NW=8 pinned
// the product at 8 (R3: af x8, wf x1). NW=4 breaks it: CG=4/NT_W=4/NPG=1 ->
// af LDS traffic HALVES while weights stay x1 (R4/R5 showed weight re-reads
// are the expensive direction). acc=128 f32/lane; 8 waves/CU -> <=256 regs.

// ------------------------------- pack kernel -------------------------------
struct PackArgs {
    const float* src[11];
    int K[11], N[11], Ntiles[11], tasks[11], dstoff[11];
};

__global__ void nerf_pack(PackArgs pa, bf16* __restrict__ dst) {
    int idx = blockIdx.x * 256 + threadIdx.x;
    for (int l = 0; l < 11; ++l) {
        if (idx < pa.tasks[l]) {
            const int lane = idx & 63;
            const int blk  = idx >> 6;
            const int nt   = blk % pa.Ntiles[l];
            const int kt   = blk / pa.Ntiles[l];
            const int kb   = kt * 32 + (lane >> 4) * 8;
            const int n    = nt * 16 + (lane & 15);
            const float* s = pa.src[l];
            const int K = pa.K[l], N = pa.N[l];
            bf16x8 v;
#pragma unroll
            for (int j = 0; j < 8; ++j) {
                int k = kb + j;
                v[j] = (bf16)((k < K && n < N) ? s[(size_t)k * N + n] : 0.f);
            }
            *(bf16x8*)(dst + pa.dstoff[l] + (size_t)idx * 8) = v;
            return;
        }
        idx -= pa.tasks[l];
    }
}

// ------------------------------- layer -------------------------------------
// Block = 256 threads = 4 waves, M=128 points. In-place C = act(H @ Wp + b).
// Operands swapped: D[m=chan][n=point].
// N=256: CG=4, NT_W=4, NPG=1, PT_W=8 -> weights once/block, af x4 (was x8).
// N=128: CG=2, NT_W=4, NPG=2, PT_W=4. N=16: CG=1, NPG=4, PT_W=2.
// COFF = source column offset (compile-time, folds into read base).
template <int KP, int N, bool RELU, int MODE, bool HAZARD, int COFF>
__device__ __forceinline__ void layer(bf16* H,
                                      const bf16* __restrict__ wp,
                                      const float* __restrict__ bias,
                                      float* __restrict__ gout, int m0) {
    constexpr int NW     = 4;
    constexpr int NTILES = N / 16;
    constexpr int NT_W   = (NTILES >= 8) ? 4 : 1;
    constexpr int CG     = NTILES / NT_W;            // chan wave-groups: 16->4, 8->2, 1->1
    static_assert(CG <= NW && NW % CG == 0, "wave split");
    constexpr int NPG0   = NW / CG;                  // point wave-groups (raw)
    constexpr int NPG    = (NPG0 > PTILES) ? PTILES : NPG0;
    constexpr int PT_W   = PTILES / NPG;             // point tiles per wave
    static_assert(NPG == NPG0 || (MODE != 0 && !HAZARD),
                  "idle waves only allowed in barrier-free modes");
    constexpr int KT = KP / 32;
    constexpr int C0 = COFF >> 3;                    // starting chunk

    const int tid  = threadIdx.x;
    const int lane = tid & 63;
    const int w    = tid >> 6;

    if constexpr (NPG != NPG0) {
        if (w / CG >= NPG) return;   // idle wave (no barriers in this mode)
    }

    const int l15  = lane & 15;
    const int quad = lane >> 4;
    const int nt0  = (w % CG) * NT_W;
    const int pt0  = (w / CG) * PT_W;

    // af read base: chunk (C0 + kt*4 + quad), point (pt0+pt)*16 + l15.
    const bf16* ar = H + (C0 + quad) * CH + (pt0 * 16 + l15) * 8;

    f32x4 acc[PT_W][NT_W];
    if constexpr (MODE == 0) {
#pragma unroll
        for (int nt = 0; nt < NT_W; ++nt) {
            f32x4 b4 = *(const f32x4*)(bias + (nt0 + nt) * 16 + quad * 4);
#pragma unroll
            for (int pt = 0; pt < PT_W; ++pt) acc[pt][nt] = b4;
        }
    } else if constexpr (MODE == 1) {
        const float bv = bias[0];
        f32x4 t = {bv, bv, bv, bv};
#pragma unroll
        for (int pt = 0; pt < PT_W; ++pt) acc[pt][0] = t;
    } else {
        f32x4 t = {bias[0], bias[1], bias[2], 0.f};
#pragma unroll
        for (int pt = 0; pt < PT_W; ++pt) acc[pt][0] = t;
    }

#pragma unroll 2
    for (int kt = 0; kt < KT; ++kt) {
        bf16x8 wf[NT_W];
#pragma unroll
        for (int nt = 0; nt < NT_W; ++nt)
            wf[nt] = *(const bf16x8*)(wp + ((size_t)(kt * NTILES + nt0 + nt) * 64 + lane) * 8);
#pragma unroll
        for (int pt = 0; pt < PT_W; ++pt) {
            bf16x8 af = *(const bf16x8*)(ar + kt * (4 * CH) + pt * 128);
#pragma unroll
            for (int nt = 0; nt < NT_W; ++nt)
                acc[pt][nt] = MFMA16(wf[nt], af, acc[pt][nt]);
        }
    }
    if (HAZARD) __syncthreads();   // all in-place reads done before writes

    if constexpr (MODE == 0) {
        // write: col c = (nt0+nt)*16 + quad*4 + r, point = (pt0+pt)*16 + l15
        // chunk = (nt0+nt)*2 + (quad>>1), in-chunk col = (quad&1)*4 + r
        bf16* wr = H + (nt0 * 2 + (quad >> 1)) * CH + (pt0 * 16 + l15) * 8 + (quad & 1) * 4;
#pragma unroll
        for (int pt = 0; pt < PT_W; ++pt) {
#pragma unroll
            for (int nt = 0; nt < NT_W; ++nt) {
                f32x4 a = acc[pt][nt];
                bf16x4 o;
#pragma unroll
                for (int r = 0; r < 4; ++r) {
                    float v = a[r];
                    if (RELU) v = v > 0.f ? v : 0.f;
                    o[r] = (bf16)v;
                }
                *(bf16x4*)(wr + nt * (2 * CH) + pt * 128) = o;
            }
        }
        __syncthreads();           // writes visible before next layer reads
    } else if constexpr (MODE == 1) {
        if (quad == 0) {
#pragma unroll
            for (int pt = 0; pt < PT_W; ++pt)
                gout[m0 + (pt0 + pt) * 16 + l15] = acc[pt][0][0];
        }
    } else {
        if (quad == 0) {
#pragma unroll
            for (int pt = 0; pt < PT_W; ++pt) {
                const size_t p3 = (size_t)(m0 + (pt0 + pt) * 16 + l15) * 3;
                gout[p3 + 0] = acc[pt][0][0];
                gout[p3 + 1] = acc[pt][0][1];
                gout[p3 + 2] = acc[pt][0][2];
            }
        }
    }
}

// ------------------------------- main kernel -------------------------------
__global__ __launch_bounds__(256, 2)
void nerf_main(const float* __restrict__ pos, const float* __restrict__ dir,
               const float* __restrict__ b0, const float* __restrict__ b1,
               const float* __restrict__ b2, const float* __restrict__ b3,
               const float* __restrict__ b4, const float* __restrict__ b5,
               const float* __restrict__ b6, const float* __restrict__ b7,
               const float* __restrict__ bd, const float* __restrict__ bc0,
               const float* __restrict__ bc1,
               const bf16* __restrict__ wpk, float* __restrict__ out) {
    __shared__ __align__(16) bf16 H[NCHUNK * CH];   // 81920 B -> 2 blocks/CU

    const int m0 = blockIdx.x * MT;
    const int tid = threadIdx.x;

    // positional encoding -> cols 256..315; 316..319 zeroed (K-pad).
    // 2 threads/row; each writes 4 contiguous 16B chunks (32 cols).
    {
        const int row = tid >> 1;          // 0..127
        const int sub = tid & 1;
        const size_t pb = (size_t)(m0 + row) * 3;
        float xs[3] = { pos[pb], pos[pb + 1], pos[pb + 2] };
#pragma unroll
        for (int h = 0; h < 4; ++h) {
            bf16x8 v;
#pragma unroll
            for (int j = 0; j < 8; ++j) {
                const int col = sub * 32 + h * 8 + j;   // 0..63
                float t = 0.f;
                if (col < 60) {
                    const int c = col / 20, rem = col % 20, s = rem / 10, i = rem % 10;
                    const float arg = xs[c] * (float)(1 << i);
                    t = s ? __cosf(arg) : __sinf(arg);
                }
                v[j] = (bf16)t;
            }
            *(bf16x8*)(H + (32 + sub * 4 + h) * CH + row * 8) = v;
        }
    }
    __syncthreads();

    // trunk, in-place; embed_pos lives in cols 256..315 until L5 consumes it
    layer<64,  256, true, 0, false, 256>(H, wpk + P0, b0, nullptr, m0);
    layer<256, 256, true, 0, true,  0  >(H, wpk + P1, b1, nullptr, m0);
    layer<256, 256, true, 0, true,  0  >(H, wpk + P2, b2, nullptr, m0);
    layer<256, 256, true, 0, true,  0  >(H, wpk + P3, b3, nullptr, m0);
    layer<256, 256, true, 0, true,  0  >(H, wpk + P4, b4, nullptr, m0);
    layer<320, 256, true, 0, true,  0  >(H, wpk + P5, b5, nullptr, m0);  // skip concat
    layer<256, 256, true, 0, true,  0  >(H, wpk + P6, b6, nullptr, m0);
    layer<256, 256, true, 0, true,  0  >(H, wpk + P7, b7, nullptr, m0);  // h8 -> cols 0..255

    // density head: reads chunks 0..31, writes global only
    layer<256, 16, false, 1, false, 0>(H, wpk + PD, bd, out, m0);

    // dir encoding -> cols 256..279; 280..287 zeroed (c0 K-pad); chunks 32..35
    // disjoint from density's reads -> no barrier before.
    {
        const int row = tid >> 1;
        const int sub = tid & 1;
        const size_t db = (size_t)(m0 + row) * 3;
        float ds[3] = { dir[db], dir[db + 1], dir[db + 2] };
#pragma unroll
        for (int h = 0; h < 2; ++h) {
            bf16x8 v;
#pragma unroll
            for (int j = 0; j < 8; ++j) {
                const int col = sub * 16 + h * 8 + j;   // 0..31
                float t = 0.f;
                if (col < 24) {
                    const int c = col / 8, rem = col % 8, s = rem / 4, i = rem % 4;
                    const float arg = ds[c] * (float)(1 << i);
                    t = s ? __cosf(arg) : __sinf(arg);
                }
                v[j] = (bf16)t;
            }
            *(bf16x8*)(H + (32 + sub * 2 + h) * CH + row * 8) = v;
        }
    }
    __syncthreads();

    // color head
    layer<288, 128, true, 0, true,  0>(H, wpk + PC0, bc0, nullptr, m0); // c0 -> cols 0..127
    layer<128, 16, false, 2, false, 0>(H, wpk + PC1, bc1, out + NPTS, m0);
}

// Loud sentinel if harness I/O layout differs from expectation.
__global__ void nerf_sentinel(float* __restrict__ out, float val) {
    if (threadIdx.x == 0 && blockIdx.x == 0) out[0] = val;
}

// ------------------------------- launcher ----------------------------------
extern "C" void kernel_launch(void* const* d_in, const int* in_sizes, int n_in,
                              void* d_out, int out_size, void* d_ws, size_t ws_size,
                              hipStream_t stream) {
    static const int exp2[24] = {
        1572864, 1572864,
        15360, 256, 65536, 256, 65536, 256, 65536, 256,
        65536, 256, 80896, 256, 65536, 256, 65536, 256,
        256, 1, 35840, 128, 384, 3
    };
    int bad = -1;
    if (n_in != 24) bad = 99;
    else {
        for (int i = 0; i < 24; ++i)
            if (in_sizes[i] != exp2[i]) { bad = i; break; }
    }
    if (bad < 0 && out_size != NPTS * 4) bad = 97;
    if (bad >= 0) {
        nerf_sentinel<<<1, 64, 0, stream>>>((float*)d_out, 20000.f + 100.f * bad);
        return;
    }

    static const int wi[11] = {2, 4, 6, 8, 10, 12, 14, 16, 18, 20, 22};
    static const int Ks[11] = {60, 256, 256, 256, 256, 316, 256, 256, 256, 280, 128};
    static const int Ns[11] = {256, 256, 256, 256, 256, 256, 256, 256, 1, 128, 3};
    static const int Kp[11] = {64, 256, 256, 256, 256, 320, 256, 256, 256, 288, 128};
    static const int Np[11] = {256, 256, 256, 256, 256, 256, 256, 256, 16, 128, 16};

    PackArgs pa;
    int off = 0, total_tasks = 0;
    for (int l = 0; l < 11; ++l) {
        pa.src[l]    = (const float*)d_in[wi[l]];
        pa.K[l]      = Ks[l];
        pa.N[l]      = Ns[l];
        pa.Ntiles[l] = Np[l] / 16;
        pa.tasks[l]  = (Kp[l] / 32) * (Np[l] / 16) * 64;
        pa.dstoff[l] = off;
        off += pa.tasks[l] * 8;
        total_tasks += pa.tasks[l];
    }
    bf16* wpk = (bf16*)d_ws;

    nerf_pack<<<(total_tasks + 255) / 256, 256, 0, stream>>>(pa, wpk);

    nerf_main<<<NPTS / MT, 256, 0, stream>>>(
        (const float*)d_in[0], (const float*)d_in[1],
        (const float*)d_in[3], (const float*)d_in[5], (const float*)d_in[7],
        (const float*)d_in[9], (const float*)d_in[11], (const float*)d_in[13],
        (const float*)d_in[15], (const float*)d_in[17], (const float*)d_in[19],
        (const float*)d_in[21], (const float*)d_in[23],
        wpk, (float*)d_out);
}